// Round 5
// baseline (369.774 us; speedup 1.0000x reference)
//
#include <hip/hip_runtime.h>
#include <math.h>

// Problem constants
constexpr int NB = 8, ND = 8, NP = 512 * 1024, NG = NP / 4, NK = 5;
constexpr int BPB  = 256;           // blocks per image
constexpr int NBLK = NB * BPB;      // 2048 blocks
constexpr int GPB  = NG / BPB;      // 512 float4-groups per block
constexpr int PSTR = 48;            // 40 sums + 5 cnts + pad

constexpr float DELTA_V = 0.5f, TWO_DELTA_D = 6.0f, GAMMA = 0.001f;
#define SCOPE __HIP_MEMORY_SCOPE_AGENT

// ws float layout:
//   [0]                        done counter (int)
//   [64   .. 64+8*48)          totals per image (released by blk==0 of each image)
//   [1024 .. 1024+NBLK*8)      per-block vsum partials (released)       (16384)
//   [32768.. 32768+45*NBLK)    K1 partials, TRANSPOSED [45][NBLK]
constexpr int OFF_TOT = 64, OFF_VP = 1024, OFF_P1 = 32768;

__device__ __forceinline__ float wave_sum(float v) {
#pragma unroll
    for (int off = 32; off > 0; off >>= 1) v += __shfl_down(v, off, 64);
    return v;
}

// ---------------- K1: per-block (k,d)-sums + counts -> partials ----------------
// waves_per_eu(2,4): grid gives at most 4 waves/EU resident; stop the scheduler
// from squeezing to a 36-VGPR schedule (R4) that serializes the 8 plane loads.
__global__ __attribute__((amdgpu_waves_per_eu(2, 4))) __launch_bounds__(256)
void k1_partials(const float* __restrict__ emb, const int* __restrict__ mask,
                 float* __restrict__ ws)
{
    const int b   = blockIdx.x / BPB;
    const int blk = blockIdx.x % BPB;
    const float4* emb4 = (const float4*)emb + (size_t)b * ND * NG;
    const int4*   m4   = (const int4*)mask + (size_t)b * NG;
    const int g0 = blk * GPB + threadIdx.x;
    const int g1 = g0 + 256;

    // All 18 loads are independent — issue them all before any compute.
    const int4 m_a = m4[g0];
    const int4 m_b = m4[g1];
    float4 e_a[ND], e_b[ND];
#pragma unroll
    for (int d = 0; d < ND; ++d) e_a[d] = emb4[(size_t)d * NG + g0];
#pragma unroll
    for (int d = 0; d < ND; ++d) e_b[d] = emb4[(size_t)d * NG + g1];

    float acc[NK][ND], cnt[NK];
#pragma unroll
    for (int k = 0; k < NK; ++k) {
        cnt[k] = 0.f;
#pragma unroll
        for (int d = 0; d < ND; ++d) acc[k][d] = 0.f;
    }

    {
        const int labs[4] = {m_a.x, m_a.y, m_a.z, m_a.w};
#pragma unroll
        for (int j = 0; j < 4; ++j) {
            const int lab = labs[j];
#pragma unroll
            for (int k = 0; k < NK; ++k) {
                const bool sel = (lab == k + 1);
                cnt[k] += sel ? 1.f : 0.f;
#pragma unroll
                for (int d = 0; d < ND; ++d)
                    acc[k][d] += sel ? ((const float*)&e_a[d])[j] : 0.f;
            }
        }
    }
    {
        const int labs[4] = {m_b.x, m_b.y, m_b.z, m_b.w};
#pragma unroll
        for (int j = 0; j < 4; ++j) {
            const int lab = labs[j];
#pragma unroll
            for (int k = 0; k < NK; ++k) {
                const bool sel = (lab == k + 1);
                cnt[k] += sel ? 1.f : 0.f;
#pragma unroll
                for (int d = 0; d < ND; ++d)
                    acc[k][d] += sel ? ((const float*)&e_b[d])[j] : 0.f;
            }
        }
    }

    __shared__ float part[4][PSTR];
    const int lane = threadIdx.x & 63, wave = threadIdx.x >> 6;
#pragma unroll
    for (int k = 0; k < NK; ++k) {
#pragma unroll
        for (int d = 0; d < ND; ++d) {
            const float r = wave_sum(acc[k][d]);
            if (lane == 0) part[wave][k * ND + d] = r;
        }
        const float rc = wave_sum(cnt[k]);
        if (lane == 0) part[wave][NK * ND + k] = rc;
    }
    __syncthreads();
    if (threadIdx.x < 45) {
        const float s = part[0][threadIdx.x] + part[1][threadIdx.x] +
                        part[2][threadIdx.x] + part[3][threadIdx.x];
        ws[OFF_P1 + (size_t)threadIdx.x * NBLK + blockIdx.x] = s;   // transposed
    }
    if (blockIdx.x == 0 && threadIdx.x == 0)
        ((int*)ws)[0] = 0;   // done-counter for K2; kernel boundary publishes
}

// ---------------- K2: hinge pass + last-block epilogue ----------------
__global__ __attribute__((amdgpu_waves_per_eu(2, 4))) __launch_bounds__(256)
void k2_hinge(const float* __restrict__ emb, const int* __restrict__ mask,
              float* __restrict__ ws, float* __restrict__ out)
{
    const int b   = blockIdx.x / BPB;
    const int blk = blockIdx.x % BPB;

    __shared__ float red1[45][4];
    __shared__ float csh[PSTR];
    __shared__ float cLDS[6][ND];    // row 0 = zeros (background)
    __shared__ float part[4][8];
    __shared__ float vred[NB][NK][4];
    __shared__ float tsh[NB][PSTR];
    __shared__ bool  amlast;

    // Preamble: reduce this image's 256 K1 partials (coalesced: [45][NBLK]).
    if (threadIdx.x < 180) {
        const int v = threadIdx.x >> 2, q = threadIdx.x & 3;
        const float* p = ws + OFF_P1 + (size_t)v * NBLK + b * BPB + q * 64;
        float s = 0.f;
#pragma unroll
        for (int i = 0; i < 64; ++i) s += p[i];
        red1[v][q] = s;
    }
    __syncthreads();
    if (threadIdx.x < 45) {
        const float s = red1[threadIdx.x][0] + red1[threadIdx.x][1] +
                        red1[threadIdx.x][2] + red1[threadIdx.x][3];
        csh[threadIdx.x] = s;
        if (blk == 0)
            __hip_atomic_store(&ws[OFF_TOT + b * PSTR + threadIdx.x], s,
                               __ATOMIC_RELEASE, SCOPE);
    }
    __syncthreads();
    if (threadIdx.x < 48) {
        const int row = threadIdx.x >> 3, d = threadIdx.x & 7;
        float v = 0.f;
        if (row > 0)
            v = csh[(row - 1) * ND + d] / fmaxf(csh[NK * ND + (row - 1)], 1.f);
        cLDS[row][d] = v;
    }
    __syncthreads();

    const float4* emb4 = (const float4*)emb + (size_t)b * ND * NG;
    const int4*   m4   = (const int4*)mask + (size_t)b * NG;
    const int g0 = blk * GPB + threadIdx.x;
    const int g1 = g0 + 256;

    const int4 m_a = m4[g0];
    const int4 m_b = m4[g1];
    float4 e_a[ND], e_b[ND];
#pragma unroll
    for (int d = 0; d < ND; ++d) e_a[d] = emb4[(size_t)d * NG + g0];
#pragma unroll
    for (int d = 0; d < ND; ++d) e_b[d] = emb4[(size_t)d * NG + g1];

    float vacc[NK] = {0.f, 0.f, 0.f, 0.f, 0.f};
    {
        const int labs[4] = {m_a.x, m_a.y, m_a.z, m_a.w};
#pragma unroll
        for (int j = 0; j < 4; ++j) {
            const int lab = labs[j];
            const float4* crow = (const float4*)&cLDS[lab][0];
            const float4 c0 = crow[0], c1 = crow[1];
            const float cd[8] = {c0.x, c0.y, c0.z, c0.w, c1.x, c1.y, c1.z, c1.w};
            float dsq = 0.f;
#pragma unroll
            for (int d = 0; d < ND; ++d) {
                const float diff = ((const float*)&e_a[d])[j] - cd[d];
                dsq = fmaf(diff, diff, dsq);
            }
            const float hv = fmaxf(sqrtf(dsq) - DELTA_V, 0.f);
            const float val = hv * hv;
#pragma unroll
            for (int k = 0; k < NK; ++k)
                vacc[k] += (lab == k + 1) ? val : 0.f;
        }
    }
    {
        const int labs[4] = {m_b.x, m_b.y, m_b.z, m_b.w};
#pragma unroll
        for (int j = 0; j < 4; ++j) {
            const int lab = labs[j];
            const float4* crow = (const float4*)&cLDS[lab][0];
            const float4 c0 = crow[0], c1 = crow[1];
            const float cd[8] = {c0.x, c0.y, c0.z, c0.w, c1.x, c1.y, c1.z, c1.w};
            float dsq = 0.f;
#pragma unroll
            for (int d = 0; d < ND; ++d) {
                const float diff = ((const float*)&e_b[d])[j] - cd[d];
                dsq = fmaf(diff, diff, dsq);
            }
            const float hv = fmaxf(sqrtf(dsq) - DELTA_V, 0.f);
            const float val = hv * hv;
#pragma unroll
            for (int k = 0; k < NK; ++k)
                vacc[k] += (lab == k + 1) ? val : 0.f;
        }
    }

    const int lane = threadIdx.x & 63, wave = threadIdx.x >> 6;
#pragma unroll
    for (int k = 0; k < NK; ++k) {
        const float r = wave_sum(vacc[k]);
        if (lane == 0) part[wave][k] = r;
    }
    __syncthreads();
    if (threadIdx.x < NK) {
        const float s = part[0][threadIdx.x] + part[1][threadIdx.x] +
                        part[2][threadIdx.x] + part[3][threadIdx.x];
        __hip_atomic_store(&ws[OFF_VP + (size_t)blockIdx.x * 8 + threadIdx.x], s,
                           __ATOMIC_RELEASE, SCOPE);
    }
    __syncthreads();
    if (threadIdx.x == 0) {
        const int old = __hip_atomic_fetch_add((int*)ws, 1, __ATOMIC_ACQ_REL, SCOPE);
        amlast = (old == NBLK - 1);
    }
    __syncthreads();
    if (!amlast) return;

    // ---- last block: gather per-image vsums + totals, compute the loss ----
    if (threadIdx.x < 160) {
        const int bb = threadIdx.x / 20, r = threadIdx.x % 20;
        const int k = r >> 2, q = r & 3;
        float s = 0.f;
#pragma unroll
        for (int i = 0; i < 64; ++i)
            s += __hip_atomic_load(&ws[OFF_VP + (size_t)(bb * BPB + q * 64 + i) * 8 + k],
                                   __ATOMIC_RELAXED, SCOPE);
        vred[bb][k][q] = s;
    }
    for (int t = threadIdx.x; t < NB * PSTR; t += 256) {
        const int bb = t / PSTR, j = t % PSTR;
        tsh[bb][j] = __hip_atomic_load(&ws[OFF_TOT + bb * PSTR + j],
                                       __ATOMIC_RELAXED, SCOPE);
    }
    __syncthreads();
    if (threadIdx.x == 0) {
        float tv = 0.f, td = 0.f, tr = 0.f, hs = 0.f;
        for (int bb = 0; bb < NB; ++bb) {
            float cc[NK], CC[NK][ND];
            bool pres[NK];
            float N = 0.f;
            for (int k = 0; k < NK; ++k) {
                cc[k] = tsh[bb][NK * ND + k];
                pres[k] = cc[k] > 0.f;
                if (pres[k]) N += 1.f;
                const float inv = 1.f / fmaxf(cc[k], 1.f);
                for (int d = 0; d < ND; ++d)
                    CC[k][d] = tsh[bb][k * ND + d] * inv;
            }
            float lv = 0.f;
            for (int k = 0; k < NK; ++k)
                if (pres[k]) {
                    const float vs = vred[bb][k][0] + vred[bb][k][1] +
                                     vred[bb][k][2] + vred[bb][k][3];
                    lv += vs / fmaxf(cc[k], 1.f);
                }
            lv /= fmaxf(N, 1.f);

            float ld = 0.f;
            for (int i2 = 0; i2 < NK; ++i2)
                for (int j2 = i2 + 1; j2 < NK; ++j2)
                    if (pres[i2] && pres[j2]) {
                        float dsq = 0.f;
                        for (int d = 0; d < ND; ++d) {
                            const float df = CC[i2][d] - CC[j2][d];
                            dsq = fmaf(df, df, dsq);
                        }
                        const float t = fmaxf(TWO_DELTA_D - sqrtf(dsq), 0.f);
                        ld += t * t;
                    }
            const float npairs = N * (N - 1.f) * 0.5f;
            ld /= (N > 1.f) ? npairs : 1.f;

            float lr = 0.f;
            for (int k = 0; k < NK; ++k)
                if (pres[k]) {
                    float sq = 0.f;
                    for (int d = 0; d < ND; ++d) sq = fmaf(CC[k][d], CC[k][d], sq);
                    lr += sqrtf(sq);
                }
            lr /= fmaxf(N, 1.f);

            if (N > 0.f) { tv += lv; td += ld; tr += lr; hs += 1.f; }
        }
        const float den = fmaxf(hs, 1.f);
        tv /= den; td /= den; tr /= den;
        out[0] = tv + td + GAMMA * tr;
        out[1] = tv;
        out[2] = td;
        out[3] = tr;
    }
}

extern "C" void kernel_launch(void* const* d_in, const int* in_sizes, int n_in,
                              void* d_out, int out_size, void* d_ws, size_t ws_size,
                              hipStream_t stream) {
    const float* emb  = (const float*)d_in[0];
    const int*   mask = (const int*)d_in[1];
    float* ws = (float*)d_ws;
    k1_partials<<<dim3(NBLK), dim3(256), 0, stream>>>(emb, mask, ws);
    k2_hinge<<<dim3(NBLK), dim3(256), 0, stream>>>(emb, mask, ws, (float*)d_out);
}